// Round 11
// baseline (297.943 us; speedup 1.0000x reference)
//
#include <hip/hip_runtime.h>

// v8: producer-consumer deform (no K-loop barriers). 6 dispatches.
// ws (19,415,056 B): xT/out1 8MB | raw 8MB | wTg1 1.18MB | wTg2 1.18MB |
//   wT61 72KB | wT62 72KB | pstats 128KB | flag 16B

typedef unsigned int u32;
typedef unsigned short u16;
typedef __attribute__((ext_vector_type(8))) short bf16x8;
typedef __attribute__((ext_vector_type(4))) float floatx4;

#define HW 4096
#define CHW 1048576

static __device__ __forceinline__ float bf2f(u16 u) {
    union { u32 i; float f; } c; c.i = ((u32)u) << 16; return c.f;
}
static __device__ __forceinline__ u16 f2bf(float f) {
    union { float f; u32 i; } c; c.f = f;
    u32 x = c.i;
    return (u16)((x + 0x7FFFu + ((x >> 16) & 1u)) >> 16);   // RNE
}
static __device__ __forceinline__ float loadv(const void* p, long i, int f32) {
    return f32 ? ((const float*)p)[i] : bf2f(((const u16*)p)[i]);
}
static __device__ __forceinline__ float lo16f(u32 w) {
    union { u32 i; float f; } c; c.i = w << 16; return c.f;
}
static __device__ __forceinline__ float hi16f(u32 w) {
    union { u32 i; float f; } c; c.i = w & 0xFFFF0000u; return c.f;
}
// pack two fp32 -> bf16 pair (round half up): out lo16 <- la, hi16 <- hb
static __device__ __forceinline__ u32 packbf(float hb, float la) {
    union { float f; u32 i; } a, b;
    a.f = la; b.f = hb;
#if __has_builtin(__builtin_amdgcn_perm)
    return __builtin_amdgcn_perm(b.i + 0x8000u, a.i + 0x8000u, 0x07060302u);
#else
    return ((b.i + 0x8000u) & 0xFFFF0000u) | ((a.i + 0x8000u) >> 16);
#endif
}

__global__ __launch_bounds__(256) void k_probe(const u32* __restrict__ xw,
                                               u32* __restrict__ flag) {
    __shared__ int cnt;
    if (threadIdx.x == 0) cnt = 0;
    __syncthreads();
    union { u32 i; float f; } c;
    c.i = xw[threadIdx.x * 997];
    float a = fabsf(c.f);
    if (a > 1e-8f && a < 1e4f) atomicAdd(&cnt, 1);
    __syncthreads();
    if (threadIdx.x == 0) { flag[0] = (cnt >= 128) ? 1u : 0u; flag[1] = 0u; }
}

// ---------------------------------------------------------------------------
// One prep kernel (unchanged from round 10).
// ---------------------------------------------------------------------------
__global__ __launch_bounds__(256) void k_prep_all(
    const void* __restrict__ x,
    const void* __restrict__ wdc1, const void* __restrict__ wdc2,
    const void* __restrict__ wtm1, const void* __restrict__ wtr1,
    const void* __restrict__ wtm2, const void* __restrict__ wtr2,
    const u32* __restrict__ flag,
    u16* __restrict__ xT, u16* __restrict__ wTg1, u16* __restrict__ wTg2,
    u16* __restrict__ wT61, u16* __restrict__ wT62)
{
    __shared__ u16 T[64 * 258];
    const int f32 = (int)flag[0];
    const int b = blockIdx.x;
    const int tid = threadIdx.x;

    if (b < 256) {
        const int n = b >> 6, h = b & 63;
        const long sb = (long)n * CHW + (h << 6);
        for (int it = 0; it < 64; ++it) {
            int e = it * 256 + tid;
            int c = e >> 6, w = e & 63;
            T[w * 258 + c] = f2bf(loadv(x, sb + (long)c * HW + w, f32));
        }
        __syncthreads();
        const int w = tid >> 2, cq = tid & 3;
        const u32* Tr = (const u32*)T;
        u16* ob = xT + (long)n * CHW + (long)((h << 6) + w) * 256 + cq * 64;
        #pragma unroll
        for (int s = 0; s < 8; ++s) {
            uint4 o;
            o.x = Tr[129 * w + 32 * cq + 4 * s + 0];
            o.y = Tr[129 * w + 32 * cq + 4 * s + 1];
            o.z = Tr[129 * w + 32 * cq + 4 * s + 2];
            o.w = Tr[129 * w + 32 * cq + 4 * s + 3];
            *(uint4*)&ob[s * 8] = o;
        }
    } else if (b < 2560) {
        const int r2 = (b >= 1408);
        const void* wdc = r2 ? wdc2 : wdc1;
        u16* wTg = r2 ? wTg2 : wTg1;
        int idx2 = (b - (r2 ? 1408 : 256)) * 256 + tid;
        int cp = idx2 & 15;
        int o  = (idx2 >> 4) & 255;
        int q  = idx2 >> 12;
        int k  = q >> 3;
        int c0 = ((q & 7) << 5) + (cp << 1);
        long s0 = (long)o * 2304 + c0 * 9 + k;
        u16 w0 = f2bf(loadv(wdc, s0, f32));
        u16 w1 = f2bf(loadv(wdc, s0 + 9, f32));
        ((u32*)wTg)[idx2] = (u32)w0 | ((u32)w1 << 16);
    } else {
        const int r2 = (b >= 2704);
        const void* wtm = r2 ? wtm2 : wtm1;
        const void* wtr = r2 ? wtr2 : wtr1;
        u16* wT6 = r2 ? wT62 : wT61;
        int i = (b - (r2 ? 2704 : 2560)) * 256 + tid;
        int q  = i >> 9;
        int o  = (i >> 5) & 15;
        int cc = i & 31;
        int k  = q >> 3;
        int c  = ((q & 7) << 5) + cc;
        float v = 0.f;
        if (o < 4)      v = loadv(wtm, (long)o * 2304 + c * 9 + k, f32);
        else if (o < 6) v = loadv(wtr, (long)(o - 4) * 2304 + c * 9 + k, f32);
        wT6[i] = f2bf(v);
    }
}

// ---------------------------------------------------------------------------
// Mega deform v8 (producer-consumer). Block = (n,h,half), 512 thr = 8 waves.
//   Stage A: offset conv (all 8 waves, barriers OK)
//   Stage B: geometry + flag init, final __syncthreads
//   Pipeline: waves 4..7 = producers (wave p owns Sl ring slot p, chunks
//     q = p+4m: sample 32px x 32ch -> Sl[p]); waves 0..3 = consumers
//     (wave w: o-range w*64..+63, 8 MFMA/chunk, depth-1 A prefetch from L2).
//   Sync: LDS rdy[4] (producer writes occupant count), fet[4] (consumers
//     atomicAdd after reading). DS ops are in-order per wave; explicit
//     s_waitcnt lgkmcnt(0) before each signal.
// ---------------------------------------------------------------------------
__global__ __launch_bounds__(512, 4) void k_deform(
    const u16* __restrict__ srcT, const u16* __restrict__ wTg,
    const u16* __restrict__ wT6,
    const void* __restrict__ b_tm, const void* __restrict__ b_tr,
    const u32* __restrict__ flag,
    u16* __restrict__ raw, float* __restrict__ pstats)
{
    __shared__ float red[8][32][17];                 // 17408 B (stage A only)
    __shared__ float tl[6 * 32];
    __shared__ __align__(16) short Sl[4][32 * 40];   // 10240 B ring
    __shared__ int   g_y0[288];
    __shared__ int   g_x0[288];
    __shared__ float g_wy[288];
    __shared__ float g_wx[288];
    __shared__ int   rdy[4];
    __shared__ int   fet[4];

    const int tid = threadIdx.x;
    const int bid = blockIdx.x;                 // n*128 + h*2 + half
    const int n = bid >> 7, h = (bid >> 1) & 63, half = bid & 1;
    const int wb = half << 5;
    const int lane = tid & 63;
    const int quad = lane >> 4;
    const int l16  = lane & 15;
    const int wv   = tid >> 6;
    const long nbase = (long)n * CHW;
    const u16* sp = srcT + nbase;

    // ---- Stage A: offset conv, 6 out-ch x 32 px (all 8 waves) ----
    {
        floatx4 acc6[2];
        acc6[0] = (floatx4){0.f, 0.f, 0.f, 0.f};
        acc6[1] = (floatx4){0.f, 0.f, 0.f, 0.f};
        for (int qi = 0; qi < 9; ++qi) {
            const int q = wv * 9 + qi;
            const int k = q >> 3, cb = q & 7;
            const int ky = k / 3, kx = k % 3;
            const int row = h + ky - 1;
            const bool rv = (row >= 0) && (row < 64);
            bf16x8 av = *(const bf16x8*)&wT6[(((q << 4) + l16) << 5) + (quad << 3)];
            #pragma unroll
            for (int j = 0; j < 2; ++j) {
                int psrc = wb + (j << 4) + l16 + kx - 1;
                bf16x8 bv = {0, 0, 0, 0, 0, 0, 0, 0};
                if (rv && psrc >= 0 && psrc < 64)
                    bv = *(const bf16x8*)&sp[(((long)(row << 6) + psrc) << 8) + (cb << 5) + (quad << 3)];
                acc6[j] = __builtin_amdgcn_mfma_f32_16x16x32_bf16(av, bv, acc6[j], 0, 0, 0);
            }
        }
        #pragma unroll
        for (int j = 0; j < 2; ++j)
            #pragma unroll
            for (int r = 0; r < 4; ++r)
                red[wv][(j << 4) + l16][(quad << 2) + r] = acc6[j][r];
        __syncthreads();
        if (tid < 192) {
            const int o = tid >> 5, px = tid & 31;
            float s = 0.f;
            #pragma unroll
            for (int v = 0; v < 8; ++v) s += red[v][px][o];
            const int f32 = (int)flag[0];
            float bias = (o < 4) ? loadv(b_tm, o, f32) : loadv(b_tr, o - 4, f32);
            tl[o * 32 + px] = s + bias;
        }
        __syncthreads();
    }

    // ---- Stage B: geometry + flag init ----
    for (int i = tid; i < 288; i += 512) {
        int k = i >> 5, ww2 = i & 31;
        float m00 = tl[ww2],       m01 = tl[32 + ww2];
        float m10 = tl[64 + ww2],  m11 = tl[96 + ww2];
        float tr0 = tl[128 + ww2], tr1 = tl[160 + ww2];
        float ry = (float)(k / 3) - 1.f;
        float rx = (float)(k % 3) - 1.f;
        float dy = m00 * ry + m01 * rx - ry + tr0;
        float dx = m10 * ry + m11 * rx - rx + tr1;
        float py = (float)h + ry + dy;
        float px = (float)(wb + ww2) + rx + dx;
        float y0f = floorf(py), x0f = floorf(px);
        g_y0[i] = (int)y0f; g_x0[i] = (int)x0f;
        g_wy[i] = py - y0f; g_wx[i] = px - x0f;
    }
    if (tid < 4) { rdy[tid] = 0; fet[tid] = 0; }
    __syncthreads();   // LAST barrier

    if (wv >= 4) {
        // ================= PRODUCER wave p: chunks q = p + 4m =================
        const int p = wv - 4;
        const int px  = lane >> 1;            // 0..31
        const int ch0 = (lane & 1) << 4;      // 0 / 16
        int cur_k = -1;
        int a00 = 0, a01 = 0, a10 = 0, a11 = 0;
        float cw00 = 0.f, cw01 = 0.f, cw10 = 0.f, cw11 = 0.f;
        volatile int* fv = fet;

        for (int m = 0; m < 18; ++m) {
            const int q = p + (m << 2);
            const int k = q >> 3;
            if (k != cur_k) {
                cur_k = k;
                int gi = (k << 5) + px;
                int y0 = g_y0[gi], x0 = g_x0[gi];
                float wy1 = g_wy[gi], wx1 = g_wx[gi];
                float wy0 = 1.f - wy1, wx0 = 1.f - wx1;
                bool yv0 = (y0 >= 0) && (y0 < 64);
                bool yv1 = (y0 >= -1) && (y0 < 63);
                bool xv0 = (x0 >= 0) && (x0 < 64);
                bool xv1 = (x0 >= -1) && (x0 < 63);
                int yc0 = min(max(y0, 0), 63),     yc1 = min(max(y0 + 1, 0), 63);
                int xc0 = min(max(x0, 0), 63),     xc1 = min(max(x0 + 1, 0), 63);
                a00 = yc0 * 64 + xc0; a01 = yc0 * 64 + xc1;
                a10 = yc1 * 64 + xc0; a11 = yc1 * 64 + xc1;
                cw00 = (yv0 && xv0) ? wy0 * wx0 : 0.f;
                cw01 = (yv0 && xv1) ? wy0 * wx1 : 0.f;
                cw10 = (yv1 && xv0) ? wy1 * wx0 : 0.f;
                cw11 = (yv1 && xv1) ? wy1 * wx1 : 0.f;
            }
            const int cc = ((q & 7) << 5) + ch0;
            // 4 corners x 16 channels (2 x uint4 each) -- issue all loads
            const u16* p00 = sp + (long)a00 * 256 + cc;
            const u16* p01 = sp + (long)a01 * 256 + cc;
            const u16* p10 = sp + (long)a10 * 256 + cc;
            const u16* p11 = sp + (long)a11 * 256 + cc;
            uint4 r00a = *(const uint4*)p00, r00b = *(const uint4*)(p00 + 8);
            uint4 r01a = *(const uint4*)p01, r01b = *(const uint4*)(p01 + 8);
            uint4 r10a = *(const uint4*)p10, r10b = *(const uint4*)(p10 + 8);
            uint4 r11a = *(const uint4*)p11, r11b = *(const uint4*)(p11 + 8);
            // wait consumers finished previous occupant of slot p
            if (m > 0) {
                while (__builtin_amdgcn_readfirstlane(fv[p]) < 4 * m)
                    __builtin_amdgcn_s_sleep(1);
            }
            u32 c00[8] = {r00a.x, r00a.y, r00a.z, r00a.w, r00b.x, r00b.y, r00b.z, r00b.w};
            u32 c01[8] = {r01a.x, r01a.y, r01a.z, r01a.w, r01b.x, r01b.y, r01b.z, r01b.w};
            u32 c10[8] = {r10a.x, r10a.y, r10a.z, r10a.w, r10b.x, r10b.y, r10b.z, r10b.w};
            u32 c11[8] = {r11a.x, r11a.y, r11a.z, r11a.w, r11b.x, r11b.y, r11b.z, r11b.w};
            u32 outv[8];
            #pragma unroll
            for (int s = 0; s < 8; ++s) {
                float la = fmaf(cw00, lo16f(c00[s]), fmaf(cw01, lo16f(c01[s]),
                           fmaf(cw10, lo16f(c10[s]), cw11 * lo16f(c11[s]))));
                float hb = fmaf(cw00, hi16f(c00[s]), fmaf(cw01, hi16f(c01[s]),
                           fmaf(cw10, hi16f(c10[s]), cw11 * hi16f(c11[s]))));
                outv[s] = packbf(hb, la);
            }
            uint4 o0; o0.x = outv[0]; o0.y = outv[1]; o0.z = outv[2]; o0.w = outv[3];
            uint4 o1; o1.x = outv[4]; o1.y = outv[5]; o1.z = outv[6]; o1.w = outv[7];
            *(uint4*)&Sl[p][px * 40 + ch0]     = o0;
            *(uint4*)&Sl[p][px * 40 + ch0 + 8] = o1;
            asm volatile("s_waitcnt lgkmcnt(0)");
            if (lane == 0) ((volatile int*)rdy)[p] = m + 1;   // publish occupant
        }
    } else {
        // ================= CONSUMER wave: o-range wv*64 .. +63 =================
        const int o0 = wv << 6;
        volatile int* rv = rdy;
        floatx4 acc[4][2];
        #pragma unroll
        for (int i = 0; i < 4; ++i) {
            acc[i][0] = (floatx4){0.f, 0.f, 0.f, 0.f};
            acc[i][1] = (floatx4){0.f, 0.f, 0.f, 0.f};
        }
        bf16x8 A[4], An[4];
        {   // prefetch A for q=0
            const u16* wp = wTg + (((size_t)0 * 256 + o0 + l16) << 5) + (quad << 3);
            A[0] = *(const bf16x8*)wp;
            A[1] = *(const bf16x8*)(wp + (16 << 5));
            A[2] = *(const bf16x8*)(wp + (32 << 5));
            A[3] = *(const bf16x8*)(wp + (48 << 5));
        }
        for (int q = 0; q < 72; ++q) {
            const int b = q & 3, m = q >> 2;
            // prefetch next A while possibly waiting
            if (q + 1 < 72) {
                const u16* wp = wTg + (((size_t)(q + 1) * 256 + o0 + l16) << 5) + (quad << 3);
                An[0] = *(const bf16x8*)wp;
                An[1] = *(const bf16x8*)(wp + (16 << 5));
                An[2] = *(const bf16x8*)(wp + (32 << 5));
                An[3] = *(const bf16x8*)(wp + (48 << 5));
            }
            while (__builtin_amdgcn_readfirstlane(rv[b]) < m + 1)
                __builtin_amdgcn_s_sleep(1);
            bf16x8 B0 = *(const bf16x8*)&Sl[b][l16 * 40 + (quad << 3)];
            bf16x8 B1 = *(const bf16x8*)&Sl[b][(16 + l16) * 40 + (quad << 3)];
            asm volatile("s_waitcnt lgkmcnt(0)");
            if (lane == 0) atomicAdd(&fet[b], 1);      // release slot
            #pragma unroll
            for (int i = 0; i < 4; ++i) {
                acc[i][0] = __builtin_amdgcn_mfma_f32_16x16x32_bf16(A[i], B0, acc[i][0], 0, 0, 0);
                acc[i][1] = __builtin_amdgcn_mfma_f32_16x16x32_bf16(A[i], B1, acc[i][1], 0, 0, 0);
            }
            #pragma unroll
            for (int i = 0; i < 4; ++i) A[i] = An[i];
        }

        // ---- GN partials (per o-tile i: groups 2i, 2i+1 of this wave) ----
        #pragma unroll
        for (int i = 0; i < 4; ++i) {
            float s1 = 0.f, s2 = 0.f;
            #pragma unroll
            for (int j = 0; j < 2; ++j)
                #pragma unroll
                for (int r = 0; r < 4; ++r) {
                    float v = acc[i][j][r];
                    s1 += v; s2 += v * v;
                }
            #pragma unroll
            for (int off = 1; off <= 16; off <<= 1) {
                s1 += __shfl_xor(s1, off, 64);
                s2 += __shfl_xor(s2, off, 64);
            }
            if ((lane & 31) == 0) {
                int g = (o0 >> 3) + 2 * i + (lane >> 5);
                pstats[((long)bid << 6) + (g << 1)]     = s1;
                pstats[((long)bid << 6) + (g << 1) + 1] = s2;
            }
        }
        // ---- raw stores ----
        #pragma unroll
        for (int i = 0; i < 4; ++i)
            #pragma unroll
            for (int j = 0; j < 2; ++j)
                #pragma unroll
                for (int r = 0; r < 4; ++r) {
                    int o = o0 + i * 16 + quad * 4 + r;
                    raw[nbase + ((long)o << 12) + (h << 6) + wb + (j << 4) + l16]
                        = f2bf(acc[i][j][r]);
                }
    }
}

// ---------------------------------------------------------------------------
// GN + relu; reduces pstats, raw NCHW -> out1 NHWC (unchanged).
// ---------------------------------------------------------------------------
__global__ __launch_bounds__(256) void k_gn_relu(
    const u16* __restrict__ raw, const float* __restrict__ pstats,
    const void* __restrict__ gamma, const void* __restrict__ beta,
    const u32* __restrict__ flag,
    u16* __restrict__ out1)
{
    __shared__ u16 T[64 * 258];
    __shared__ float sred[4][64];
    __shared__ float sl[64];
    const int f32 = (int)flag[0];
    const int bid = blockIdx.x;
    const int n = bid >> 6, h = bid & 63;
    const int tid = threadIdx.x;

    {
        const int v = tid & 63, part = tid >> 6;
        float a = 0.f;
        for (int j = part * 32; j < part * 32 + 32; ++j)
            a += pstats[(((long)n * 128 + j) << 6) + v];
        sred[part][v] = a;
        __syncthreads();
        if (tid < 64) sl[tid] = sred[0][tid] + sred[1][tid] + sred[2][tid] + sred[3][tid];
        __syncthreads();
    }

    const u16* rb = raw + (long)n * CHW + (h << 6);
    for (int it = 0; it < 64; ++it) {
        int e = it * 256 + tid;
        int c = e >> 6, w = e & 63;
        int g = c >> 3;
        float mean = sl[g * 2] * (1.f / 32768.f);
        float var  = sl[g * 2 + 1] * (1.f / 32768.f) - mean * mean;
        float rstd = rsqrtf(var + 1e-5f);
        float ga = loadv(gamma, c, f32) * rstd;
        float be = loadv(beta, c, f32) - mean * ga;
        float v = fmaxf(fmaf(bf2f(rb[(long)c * HW + w]), ga, be), 0.f);
        T[w * 258 + c] = f2bf(v);
    }
    __syncthreads();
    const int w = tid >> 2, cq = tid & 3;
    const u32* Tr = (const u32*)T;
    u16* ob = out1 + (long)n * CHW + (long)((h << 6) + w) * 256 + cq * 64;
    #pragma unroll
    for (int s = 0; s < 8; ++s) {
        uint4 o;
        o.x = Tr[129 * w + 32 * cq + 4 * s + 0];
        o.y = Tr[129 * w + 32 * cq + 4 * s + 1];
        o.z = Tr[129 * w + 32 * cq + 4 * s + 2];
        o.w = Tr[129 * w + 32 * cq + 4 * s + 3];
        *(uint4*)&ob[s * 8] = o;
    }
}

// ---------------------------------------------------------------------------
// Final GN + residual + relu (unchanged).
// ---------------------------------------------------------------------------
__global__ __launch_bounds__(256) void k_gn_final(
    const u16* __restrict__ raw, const float* __restrict__ pstats,
    const void* __restrict__ gamma, const void* __restrict__ beta,
    const void* __restrict__ x, const u32* __restrict__ flag,
    void* __restrict__ outp)
{
    __shared__ float rr[256];
    const int f32 = (int)flag[0];
    const int tid = threadIdx.x;
    const long e0 = ((long)blockIdx.x) << 11;
    const int n = (int)(e0 >> 20);
    const int c0 = (int)((e0 >> 12) & 255);
    const int g = c0 >> 3;

    {
        int j = tid & 127, sv = tid >> 7;
        rr[tid] = pstats[(((long)n * 128 + j) << 6) + (g << 1) + sv];
        __syncthreads();
        #pragma unroll
        for (int s = 64; s >= 1; s >>= 1) {
            if ((tid & 127) < s) rr[tid] += rr[tid + s];
            __syncthreads();
        }
    }
    float mean = rr[0] * (1.f / 32768.f);
    float var  = rr[128] * (1.f / 32768.f) - mean * mean;
    float rstd = rsqrtf(var + 1e-5f);

    const long i = blockIdx.x * 256 + tid;
    const long e = i << 3;
    const int c = (int)((e >> 12) & 255);
    float ga = loadv(gamma, c, f32) * rstd;
    float be = loadv(beta, c, f32) - mean * ga;
    uint4 p = ((const uint4*)raw)[i];
    u32 ww[4] = {p.x, p.y, p.z, p.w};
    float v[8];
    #pragma unroll
    for (int q = 0; q < 4; ++q) {
        v[2 * q + 0] = fmaxf(fmaf(bf2f((u16)(ww[q] & 0xFFFFu)), ga, be) + loadv(x, e + 2 * q + 0, f32), 0.f);
        v[2 * q + 1] = fmaxf(fmaf(bf2f((u16)(ww[q] >> 16)),     ga, be) + loadv(x, e + 2 * q + 1, f32), 0.f);
    }
    if (f32) {
        float4* op = (float4*)((float*)outp + e);
        op[0] = make_float4(v[0], v[1], v[2], v[3]);
        op[1] = make_float4(v[4], v[5], v[6], v[7]);
    } else {
        uint4 o;
        o.x = (u32)f2bf(v[0]) | ((u32)f2bf(v[1]) << 16);
        o.y = (u32)f2bf(v[2]) | ((u32)f2bf(v[3]) << 16);
        o.z = (u32)f2bf(v[4]) | ((u32)f2bf(v[5]) << 16);
        o.w = (u32)f2bf(v[6]) | ((u32)f2bf(v[7]) << 16);
        ((uint4*)outp)[i] = o;
    }
}

extern "C" void kernel_launch(void* const* d_in, const int* in_sizes, int n_in,
                              void* d_out, int out_size, void* d_ws, size_t ws_size,
                              hipStream_t stream) {
    const void* x     = d_in[0];
    const void* w_tm1 = d_in[1];
    const void* b_tm1 = d_in[2];
    const void* w_tr1 = d_in[3];
    const void* b_tr1 = d_in[4];
    const void* w_dc1 = d_in[5];
    const void* g1    = d_in[6];
    const void* be1   = d_in[7];
    const void* w_tm2 = d_in[8];
    const void* b_tm2 = d_in[9];
    const void* w_tr2 = d_in[10];
    const void* b_tr2 = d_in[11];
    const void* w_dc2 = d_in[12];
    const void* g2    = d_in[13];
    const void* be2   = d_in[14];

    char* wsb = (char*)d_ws;
    u16*   xT     = (u16*)wsb;
    u16*   raw    = (u16*)(wsb + 8388608);
    u16*   wTg1   = (u16*)(wsb + 16777216);
    u16*   wTg2   = (u16*)(wsb + 17956864);
    u16*   wT61   = (u16*)(wsb + 19136512);
    u16*   wT62   = (u16*)(wsb + 19210240);
    float* pstats = (float*)(wsb + 19283968);
    u32*   flag   = (u32*)(wsb + 19415040);
    u16*   out1   = xT;

    k_probe   <<<1, 256, 0, stream>>>((const u32*)x, flag);
    k_prep_all<<<2848, 256, 0, stream>>>(x, w_dc1, w_dc2, w_tm1, w_tr1, w_tm2, w_tr2,
                                         flag, xT, wTg1, wTg2, wT61, wT62);
    // ---- round 1 ----
    k_deform  <<<512, 512, 0, stream>>>(xT, wTg1, wT61, b_tm1, b_tr1, flag, raw, pstats);
    k_gn_relu <<<256, 256, 0, stream>>>(raw, pstats, g1, be1, flag, out1);
    // ---- round 2 ----
    k_deform  <<<512, 512, 0, stream>>>(out1, wTg2, wT62, b_tm2, b_tr2, flag, raw, pstats);
    k_gn_final<<<2048, 256, 0, stream>>>(raw, pstats, g2, be2, x, flag, d_out);
}

// Round 12
// 255.236 us; speedup vs baseline: 1.1673x; 1.1673x over previous
//
#include <hip/hip_runtime.h>

// v9: round-10 deform (proven best) + inline dtype sniff (k_probe dispatch
// removed) + vectorized transpose loops. 5 dispatches.
// ws (19,415,040 B): xT/out1 8MB | raw 8MB | wTg1 1.18MB | wTg2 1.18MB |
//   wT61 72KB | wT62 72KB | pstats 128KB

typedef unsigned int u32;
typedef unsigned short u16;
typedef __attribute__((ext_vector_type(8))) short bf16x8;
typedef __attribute__((ext_vector_type(4))) float floatx4;

#define HW 4096
#define CHW 1048576

static __device__ __forceinline__ float bf2f(u16 u) {
    union { u32 i; float f; } c; c.i = ((u32)u) << 16; return c.f;
}
static __device__ __forceinline__ u16 f2bf(float f) {
    union { float f; u32 i; } c; c.f = f;
    u32 x = c.i;
    return (u16)((x + 0x7FFFu + ((x >> 16) & 1u)) >> 16);   // RNE
}
static __device__ __forceinline__ float loadv(const void* p, long i, int f32) {
    return f32 ? ((const float*)p)[i] : bf2f(((const u16*)p)[i]);
}
// Inline dtype sniff: 16 fixed words of x interpreted as fp32; genuine fp32
// N(0,1) data has sane magnitudes. Wave-uniform (scalar loads). Same
// decision rule as the old k_probe (50% threshold).
static __device__ __forceinline__ int sniff_f32(const u32* __restrict__ xw) {
    int cnt = 0;
    #pragma unroll
    for (int s = 0; s < 16; ++s) {
        union { u32 i; float f; } c;
        c.i = xw[s * 131 + 7];
        float a = fabsf(c.f);
        if (a > 1e-8f && a < 1e4f) ++cnt;
    }
    return (cnt >= 8) ? 1 : 0;
}

// ---------------------------------------------------------------------------
// One prep kernel: blocks [0,256) NCHW->NHWC transpose (vectorized);
// [256,1408) wTg1; [1408,2560) wTg2; [2560,2704) wT61; [2704,2848) wT62.
// ---------------------------------------------------------------------------
__global__ __launch_bounds__(256) void k_prep_all(
    const void* __restrict__ x,
    const void* __restrict__ wdc1, const void* __restrict__ wdc2,
    const void* __restrict__ wtm1, const void* __restrict__ wtr1,
    const void* __restrict__ wtm2, const void* __restrict__ wtr2,
    u16* __restrict__ xT, u16* __restrict__ wTg1, u16* __restrict__ wTg2,
    u16* __restrict__ wT61, u16* __restrict__ wT62)
{
    __shared__ u16 T[64 * 258];
    const int f32 = sniff_f32((const u32*)x);
    const int b = blockIdx.x;
    const int tid = threadIdx.x;

    if (b < 256) {                       // ---- NCHW -> NHWC (LDS transpose)
        const int n = b >> 6, h = b & 63;
        const long sb = (long)n * CHW + (h << 6);
        const int cb = tid >> 3;         // 0..31
        const int w0 = (tid & 7) << 3;   // 0..56
        if (f32) {
            const float* xp = (const float*)x;
            for (int it = 0; it < 8; ++it) {
                int c = (it << 5) + cb;
                const float* pr = xp + sb + (long)c * HW + w0;
                float4 a = ((const float4*)pr)[0];
                float4 d = ((const float4*)pr)[1];
                T[(w0 + 0) * 258 + c] = f2bf(a.x);
                T[(w0 + 1) * 258 + c] = f2bf(a.y);
                T[(w0 + 2) * 258 + c] = f2bf(a.z);
                T[(w0 + 3) * 258 + c] = f2bf(a.w);
                T[(w0 + 4) * 258 + c] = f2bf(d.x);
                T[(w0 + 5) * 258 + c] = f2bf(d.y);
                T[(w0 + 6) * 258 + c] = f2bf(d.z);
                T[(w0 + 7) * 258 + c] = f2bf(d.w);
            }
        } else {
            const u16* xp = (const u16*)x;
            for (int it = 0; it < 8; ++it) {
                int c = (it << 5) + cb;
                uint4 v = *(const uint4*)(xp + sb + (long)c * HW + w0);
                u32 ws[4] = {v.x, v.y, v.z, v.w};
                #pragma unroll
                for (int q = 0; q < 4; ++q) {
                    T[(w0 + 2 * q + 0) * 258 + c] = (u16)(ws[q] & 0xFFFFu);
                    T[(w0 + 2 * q + 1) * 258 + c] = (u16)(ws[q] >> 16);
                }
            }
        }
        __syncthreads();
        const int w = tid >> 2, cq = tid & 3;
        const u32* Tr = (const u32*)T;
        u16* ob = xT + (long)n * CHW + (long)((h << 6) + w) * 256 + cq * 64;
        #pragma unroll
        for (int s = 0; s < 8; ++s) {
            uint4 o;
            o.x = Tr[129 * w + 32 * cq + 4 * s + 0];
            o.y = Tr[129 * w + 32 * cq + 4 * s + 1];
            o.z = Tr[129 * w + 32 * cq + 4 * s + 2];
            o.w = Tr[129 * w + 32 * cq + 4 * s + 3];
            *(uint4*)&ob[s * 8] = o;
        }
    } else if (b < 2560) {               // ---- deform weights (both rounds)
        const int r2 = (b >= 1408);
        const void* wdc = r2 ? wdc2 : wdc1;
        u16* wTg = r2 ? wTg2 : wTg1;
        int idx2 = (b - (r2 ? 1408 : 256)) * 256 + tid;   // 0..294911
        int cp = idx2 & 15;
        int o  = (idx2 >> 4) & 255;
        int q  = idx2 >> 12;
        int k  = q >> 3;
        int c0 = ((q & 7) << 5) + (cp << 1);
        long s0 = (long)o * 2304 + c0 * 9 + k;
        u16 w0 = f2bf(loadv(wdc, s0, f32));
        u16 w1 = f2bf(loadv(wdc, s0 + 9, f32));
        ((u32*)wTg)[idx2] = (u32)w0 | ((u32)w1 << 16);
    } else {                             // ---- offset-conv weights
        const int r2 = (b >= 2704);
        const void* wtm = r2 ? wtm2 : wtm1;
        const void* wtr = r2 ? wtr2 : wtr1;
        u16* wT6 = r2 ? wT62 : wT61;
        int i = (b - (r2 ? 2704 : 2560)) * 256 + tid;     // 0..36863
        int q  = i >> 9;
        int o  = (i >> 5) & 15;
        int cc = i & 31;
        int k  = q >> 3;
        int c  = ((q & 7) << 5) + cc;
        float v = 0.f;
        if (o < 4)      v = loadv(wtm, (long)o * 2304 + c * 9 + k, f32);
        else if (o < 6) v = loadv(wtr, (long)(o - 4) * 2304 + c * 9 + k, f32);
        wT6[i] = f2bf(v);
    }
}

// ---------------------------------------------------------------------------
// Mega deform (round-10 structure, proven 70.7 µs): per (n,h,half) block:
//   Stage A: offset conv (MFMA) -> tmtr slice in LDS
//   Stage B: build_offset geometry
//   Stage C: barriered K-loop, A-frags direct from L2 wTg
//   Stage D: GN partials -> pstats[bid][64] (plain stores, no atomics)
//   Stage E: raw (NCHW bf16) stores
// ---------------------------------------------------------------------------
__global__ __launch_bounds__(512, 4) void k_deform(
    const u16* __restrict__ srcT, const u16* __restrict__ wTg,
    const u16* __restrict__ wT6,
    const void* __restrict__ b_tm, const void* __restrict__ b_tr,
    const u32* __restrict__ xw,
    u16* __restrict__ raw, float* __restrict__ pstats)
{
    __shared__ float red[8][32][17];                 // 17408 B (stage A)
    __shared__ float tl[6 * 32];                     //   768 B
    __shared__ __align__(16) short Sl[2][32 * 40];   //  5120 B
    __shared__ int   g_y0[288];
    __shared__ int   g_x0[288];
    __shared__ float g_wy[288];
    __shared__ float g_wx[288];

    const int tid = threadIdx.x;
    const int bid = blockIdx.x;                 // n*128 + h*2 + half
    const int n = bid >> 7, h = (bid >> 1) & 63, half = bid & 1;
    const int wb = half << 5;
    const int lane = tid & 63;
    const int quad = lane >> 4;
    const int l16  = lane & 15;
    const int wv   = tid >> 6;
    const long nbase = (long)n * CHW;
    const u16* sp = srcT + nbase;

    // ---- Stage A: offset conv, 6 out-ch x 32 px ----
    {
        floatx4 acc6[2];
        acc6[0] = (floatx4){0.f, 0.f, 0.f, 0.f};
        acc6[1] = (floatx4){0.f, 0.f, 0.f, 0.f};
        for (int qi = 0; qi < 9; ++qi) {
            const int q = wv * 9 + qi;
            const int k = q >> 3, cb = q & 7;
            const int ky = k / 3, kx = k % 3;
            const int row = h + ky - 1;
            const bool rv = (row >= 0) && (row < 64);
            bf16x8 av = *(const bf16x8*)&wT6[(((q << 4) + l16) << 5) + (quad << 3)];
            #pragma unroll
            for (int j = 0; j < 2; ++j) {
                int psrc = wb + (j << 4) + l16 + kx - 1;
                bf16x8 bv = {0, 0, 0, 0, 0, 0, 0, 0};
                if (rv && psrc >= 0 && psrc < 64)
                    bv = *(const bf16x8*)&sp[(((long)(row << 6) + psrc) << 8) + (cb << 5) + (quad << 3)];
                acc6[j] = __builtin_amdgcn_mfma_f32_16x16x32_bf16(av, bv, acc6[j], 0, 0, 0);
            }
        }
        #pragma unroll
        for (int j = 0; j < 2; ++j)
            #pragma unroll
            for (int r = 0; r < 4; ++r)
                red[wv][(j << 4) + l16][(quad << 2) + r] = acc6[j][r];
        __syncthreads();
        if (tid < 192) {
            const int o = tid >> 5, px = tid & 31;
            float s = 0.f;
            #pragma unroll
            for (int v = 0; v < 8; ++v) s += red[v][px][o];
            const int f32 = sniff_f32(xw);
            float bias = (o < 4) ? loadv(b_tm, o, f32) : loadv(b_tr, o - 4, f32);
            tl[o * 32 + px] = s + bias;
        }
        __syncthreads();
    }

    // ---- Stage B: geometry for 9 taps x 32 px ----
    for (int i = tid; i < 288; i += 512) {
        int k = i >> 5, ww2 = i & 31;
        float m00 = tl[ww2],       m01 = tl[32 + ww2];
        float m10 = tl[64 + ww2],  m11 = tl[96 + ww2];
        float tr0 = tl[128 + ww2], tr1 = tl[160 + ww2];
        float ry = (float)(k / 3) - 1.f;
        float rx = (float)(k % 3) - 1.f;
        float dy = m00 * ry + m01 * rx - ry + tr0;
        float dx = m10 * ry + m11 * rx - rx + tr1;
        float py = (float)h + ry + dy;
        float px = (float)(wb + ww2) + rx + dx;
        float y0f = floorf(py), x0f = floorf(px);
        g_y0[i] = (int)y0f; g_x0[i] = (int)x0f;
        g_wy[i] = py - y0f; g_wx[i] = px - x0f;
    }
    __syncthreads();

    // ---- Stage C: main K-loop ----
    const int sw  = tid >> 4;      // px 0..31
    const int scq = tid & 15;      // channel pair
    const int o0  = wv << 5;

    floatx4 acc[2][2];
    #pragma unroll
    for (int i = 0; i < 2; ++i)
        #pragma unroll
        for (int j = 0; j < 2; ++j)
            acc[i][j] = (floatx4){0.f, 0.f, 0.f, 0.f};

    int a00 = 0, a01 = 0, a10 = 0, a11 = 0;
    float cw00 = 0.f, cw01 = 0.f, cw10 = 0.f, cw11 = 0.f;
    int cur_k = -1;
    u32 s00 = 0, s01 = 0, s10 = 0, s11 = 0;
    bf16x8 wa = {0,0,0,0,0,0,0,0}, wbv = {0,0,0,0,0,0,0,0};

    auto issue = [&](int q) {
        const int k = q >> 3;
        if (k != cur_k) {
            cur_k = k;
            int gi = (k << 5) + sw;
            int y0 = g_y0[gi], x0 = g_x0[gi];
            float wy1 = g_wy[gi], wx1 = g_wx[gi];
            float wy0 = 1.f - wy1, wx0 = 1.f - wx1;
            bool yv0 = (y0 >= 0) && (y0 < 64);
            bool yv1 = (y0 >= -1) && (y0 < 63);
            bool xv0 = (x0 >= 0) && (x0 < 64);
            bool xv1 = (x0 >= -1) && (x0 < 63);
            int yc0 = min(max(y0, 0), 63),     yc1 = min(max(y0 + 1, 0), 63);
            int xc0 = min(max(x0, 0), 63),     xc1 = min(max(x0 + 1, 0), 63);
            a00 = yc0 * 64 + xc0; a01 = yc0 * 64 + xc1;
            a10 = yc1 * 64 + xc0; a11 = yc1 * 64 + xc1;
            cw00 = (yv0 && xv0) ? wy0 * wx0 : 0.f;
            cw01 = (yv0 && xv1) ? wy0 * wx1 : 0.f;
            cw10 = (yv1 && xv0) ? wy1 * wx0 : 0.f;
            cw11 = (yv1 && xv1) ? wy1 * wx1 : 0.f;
        }
        const int cc = ((q & 7) << 5) + (scq << 1);   // 2 channels
        s00 = *(const u32*)&sp[(long)a00 * 256 + cc];
        s01 = *(const u32*)&sp[(long)a01 * 256 + cc];
        s10 = *(const u32*)&sp[(long)a10 * 256 + cc];
        s11 = *(const u32*)&sp[(long)a11 * 256 + cc];
        const u16* wp = wTg + (((size_t)q * 256 + o0 + l16) << 5) + (quad << 3);
        wa  = *(const bf16x8*)wp;
        wbv = *(const bf16x8*)(wp + (16 << 5));
    };
    auto publish = [&](int b) {
        float va = fmaf(cw00, bf2f((u16)s00),
                   fmaf(cw01, bf2f((u16)s01),
                   fmaf(cw10, bf2f((u16)s10), cw11 * bf2f((u16)s11))));
        float vb = fmaf(cw00, bf2f((u16)(s00 >> 16)),
                   fmaf(cw01, bf2f((u16)(s01 >> 16)),
                   fmaf(cw10, bf2f((u16)(s10 >> 16)), cw11 * bf2f((u16)(s11 >> 16)))));
        *(u32*)&Sl[b][sw * 40 + (scq << 1)] = (u32)f2bf(va) | ((u32)f2bf(vb) << 16);
    };

    issue(0);
    publish(0);
    bf16x8 A0 = wa, A1 = wbv;
    __syncthreads();

    for (int q = 0; q < 72; ++q) {
        if (q + 1 < 72) issue(q + 1);
        {
            const int b = q & 1;
            #pragma unroll
            for (int j = 0; j < 2; ++j) {
                bf16x8 bv = *(const bf16x8*)&Sl[b][((j << 4) + l16) * 40 + (quad << 3)];
                acc[0][j] = __builtin_amdgcn_mfma_f32_16x16x32_bf16(A0, bv, acc[0][j], 0, 0, 0);
                acc[1][j] = __builtin_amdgcn_mfma_f32_16x16x32_bf16(A1, bv, acc[1][j], 0, 0, 0);
            }
        }
        if (q + 1 < 72) { publish((q + 1) & 1); A0 = wa; A1 = wbv; }
        __syncthreads();
    }

    // ---- Stage D: GN partials (no atomics) ----
    #pragma unroll
    for (int i = 0; i < 2; ++i) {
        float s1 = 0.f, s2 = 0.f;
        #pragma unroll
        for (int j = 0; j < 2; ++j)
            #pragma unroll
            for (int r = 0; r < 4; ++r) {
                float v = acc[i][j][r];
                s1 += v; s2 += v * v;
            }
        #pragma unroll
        for (int off = 1; off <= 16; off <<= 1) {
            s1 += __shfl_xor(s1, off, 64);
            s2 += __shfl_xor(s2, off, 64);
        }
        if ((lane & 31) == 0) {
            int g = (o0 >> 3) + 2 * i + (lane >> 5);
            pstats[((long)bid << 6) + (g << 1)]     = s1;
            pstats[((long)bid << 6) + (g << 1) + 1] = s2;
        }
    }

    // ---- Stage E: raw stores ----
    #pragma unroll
    for (int i = 0; i < 2; ++i)
        #pragma unroll
        for (int j = 0; j < 2; ++j)
            #pragma unroll
            for (int r = 0; r < 4; ++r) {
                int o = o0 + i * 16 + quad * 4 + r;
                raw[nbase + ((long)o << 12) + (h << 6) + wb + (j << 4) + l16]
                    = f2bf(acc[i][j][r]);
            }
}

// ---------------------------------------------------------------------------
// GN + relu; reduces pstats, raw NCHW -> out1 NHWC (vectorized loads).
// ---------------------------------------------------------------------------
__global__ __launch_bounds__(256) void k_gn_relu(
    const u16* __restrict__ raw, const float* __restrict__ pstats,
    const void* __restrict__ gamma, const void* __restrict__ beta,
    const u32* __restrict__ xw,
    u16* __restrict__ out1)
{
    __shared__ u16 T[64 * 258];
    __shared__ float sred[4][64];
    __shared__ float sl[64];
    const int f32 = sniff_f32(xw);
    const int bid = blockIdx.x;
    const int n = bid >> 6, h = bid & 63;
    const int tid = threadIdx.x;

    {   // reduce partials: value v over 128 blocks of this n
        const int v = tid & 63, part = tid >> 6;
        float a = 0.f;
        for (int j = part * 32; j < part * 32 + 32; ++j)
            a += pstats[(((long)n * 128 + j) << 6) + v];
        sred[part][v] = a;
        __syncthreads();
        if (tid < 64) sl[tid] = sred[0][tid] + sred[1][tid] + sred[2][tid] + sred[3][tid];
        __syncthreads();
    }

    const u16* rb = raw + (long)n * CHW + (h << 6);
    const int cb = tid >> 3;         // 0..31
    const int w0 = (tid & 7) << 3;   // 0..56
    for (int it = 0; it < 8; ++it) {
        int c = (it << 5) + cb;
        int g = c >> 3;
        float mean = sl[g * 2] * (1.f / 32768.f);
        float var  = sl[g * 2 + 1] * (1.f / 32768.f) - mean * mean;
        float rstd = rsqrtf(var + 1e-5f);
        float ga = loadv(gamma, c, f32) * rstd;
        float be = loadv(beta, c, f32) - mean * ga;
        uint4 v = *(const uint4*)(rb + (long)c * HW + w0);
        u32 ws[4] = {v.x, v.y, v.z, v.w};
        #pragma unroll
        for (int q = 0; q < 4; ++q) {
            float a = fmaxf(fmaf(bf2f((u16)(ws[q] & 0xFFFFu)), ga, be), 0.f);
            float b = fmaxf(fmaf(bf2f((u16)(ws[q] >> 16)),     ga, be), 0.f);
            T[(w0 + 2 * q + 0) * 258 + c] = f2bf(a);
            T[(w0 + 2 * q + 1) * 258 + c] = f2bf(b);
        }
    }
    __syncthreads();
    const int w = tid >> 2, cq = tid & 3;
    const u32* Tr = (const u32*)T;
    u16* ob = out1 + (long)n * CHW + (long)((h << 6) + w) * 256 + cq * 64;
    #pragma unroll
    for (int s = 0; s < 8; ++s) {
        uint4 o;
        o.x = Tr[129 * w + 32 * cq + 4 * s + 0];
        o.y = Tr[129 * w + 32 * cq + 4 * s + 1];
        o.z = Tr[129 * w + 32 * cq + 4 * s + 2];
        o.w = Tr[129 * w + 32 * cq + 4 * s + 3];
        *(uint4*)&ob[s * 8] = o;
    }
}

// ---------------------------------------------------------------------------
// Final GN + residual + relu (per-block partial reduction, unchanged).
// ---------------------------------------------------------------------------
__global__ __launch_bounds__(256) void k_gn_final(
    const u16* __restrict__ raw, const float* __restrict__ pstats,
    const void* __restrict__ gamma, const void* __restrict__ beta,
    const void* __restrict__ x,
    void* __restrict__ outp)
{
    __shared__ float rr[256];
    const int f32 = sniff_f32((const u32*)x);
    const int tid = threadIdx.x;
    const long e0 = ((long)blockIdx.x) << 11;
    const int n = (int)(e0 >> 20);
    const int c0 = (int)((e0 >> 12) & 255);
    const int g = c0 >> 3;

    {
        int j = tid & 127, sv = tid >> 7;
        rr[tid] = pstats[(((long)n * 128 + j) << 6) + (g << 1) + sv];
        __syncthreads();
        #pragma unroll
        for (int s = 64; s >= 1; s >>= 1) {
            if ((tid & 127) < s) rr[tid] += rr[tid + s];
            __syncthreads();
        }
    }
    float mean = rr[0] * (1.f / 32768.f);
    float var  = rr[128] * (1.f / 32768.f) - mean * mean;
    float rstd = rsqrtf(var + 1e-5f);

    const long i = blockIdx.x * 256 + tid;
    const long e = i << 3;
    const int c = (int)((e >> 12) & 255);
    float ga = loadv(gamma, c, f32) * rstd;
    float be = loadv(beta, c, f32) - mean * ga;
    uint4 p = ((const uint4*)raw)[i];
    u32 ww[4] = {p.x, p.y, p.z, p.w};
    float v[8];
    #pragma unroll
    for (int q = 0; q < 4; ++q) {
        v[2 * q + 0] = fmaxf(fmaf(bf2f((u16)(ww[q] & 0xFFFFu)), ga, be) + loadv(x, e + 2 * q + 0, f32), 0.f);
        v[2 * q + 1] = fmaxf(fmaf(bf2f((u16)(ww[q] >> 16)),     ga, be) + loadv(x, e + 2 * q + 1, f32), 0.f);
    }
    if (f32) {
        float4* op = (float4*)((float*)outp + e);
        op[0] = make_float4(v[0], v[1], v[2], v[3]);
        op[1] = make_float4(v[4], v[5], v[6], v[7]);
    } else {
        uint4 o;
        o.x = (u32)f2bf(v[0]) | ((u32)f2bf(v[1]) << 16);
        o.y = (u32)f2bf(v[2]) | ((u32)f2bf(v[3]) << 16);
        o.z = (u32)f2bf(v[4]) | ((u32)f2bf(v[5]) << 16);
        o.w = (u32)f2bf(v[6]) | ((u32)f2bf(v[7]) << 16);
        ((uint4*)outp)[i] = o;
    }
}

extern "C" void kernel_launch(void* const* d_in, const int* in_sizes, int n_in,
                              void* d_out, int out_size, void* d_ws, size_t ws_size,
                              hipStream_t stream) {
    const void* x     = d_in[0];
    const void* w_tm1 = d_in[1];
    const void* b_tm1 = d_in[2];
    const void* w_tr1 = d_in[3];
    const void* b_tr1 = d_in[4];
    const void* w_dc1 = d_in[5];
    const void* g1    = d_in[6];
    const void* be1   = d_in[7];
    const void* w_tm2 = d_in[8];
    const void* b_tm2 = d_in[9];
    const void* w_tr2 = d_in[10];
    const void* b_tr2 = d_in[11];
    const void* w_dc2 = d_in[12];
    const void* g2    = d_in[13];
    const void* be2   = d_in[14];

    char* wsb = (char*)d_ws;
    u16*   xT     = (u16*)wsb;                       // 8,388,608 (alias out1)
    u16*   raw    = (u16*)(wsb + 8388608);           // 8,388,608
    u16*   wTg1   = (u16*)(wsb + 16777216);          // 1,179,648
    u16*   wTg2   = (u16*)(wsb + 17956864);          // 1,179,648
    u16*   wT61   = (u16*)(wsb + 19136512);          //    73,728
    u16*   wT62   = (u16*)(wsb + 19210240);          //    73,728
    float* pstats = (float*)(wsb + 19283968);        //   131,072
    u16*   out1   = xT;
    const u32* xw = (const u32*)x;

    k_prep_all<<<2848, 256, 0, stream>>>(x, w_dc1, w_dc2, w_tm1, w_tr1, w_tm2, w_tr2,
                                         xT, wTg1, wTg2, wT61, wT62);
    // ---- round 1 ----
    k_deform  <<<512, 512, 0, stream>>>(xT, wTg1, wT61, b_tm1, b_tr1, xw, raw, pstats);
    k_gn_relu <<<256, 256, 0, stream>>>(raw, pstats, g1, be1, xw, out1);
    // ---- round 2 ----
    k_deform  <<<512, 512, 0, stream>>>(out1, wTg2, wT62, b_tm2, b_tr2, xw, raw, pstats);
    k_gn_final<<<2048, 256, 0, stream>>>(raw, pstats, g2, be2, x, d_out);
}